// Round 2
// 736.743 us; speedup vs baseline: 1.0441x; 1.0441x over previous
//
#include <hip/hip_runtime.h>

#define NUQ 50000
#define NIQ 50000
#define DQ 256
#define NTOT 100000
#define LALPHA 0.2f
#define GPE 782   // gemm blocks per entity = ceil(50000/64)

typedef __attribute__((ext_vector_type(8))) __bf16 bf16x8;
typedef __attribute__((ext_vector_type(4))) float floatx4;
typedef __attribute__((ext_vector_type(8))) unsigned short ushort8;

__device__ __forceinline__ float b2f(unsigned short u) {
    unsigned int x = ((unsigned int)u) << 16;
    return __builtin_bit_cast(float, x);
}
__device__ __forceinline__ unsigned short f2b(float f) {
    unsigned int u = __builtin_bit_cast(unsigned int, f);
    u = u + 0x7FFFu + ((u >> 16) & 1u);   // round-to-nearest-even
    return (unsigned short)(u >> 16);
}

#define GLD_LDS16(g, l)                                                        \
    __builtin_amdgcn_global_load_lds(                                          \
        (const __attribute__((address_space(1))) void*)(g),                    \
        (__attribute__((address_space(3))) void*)(l), 16, 0, 0)

// ---------------------------------------------------------------------------
// CSR row_ptr from sorted rows[].
// ---------------------------------------------------------------------------
__global__ __launch_bounds__(256) void build_rowptr(
    const int* __restrict__ rows, int nnz, int* __restrict__ rptr, int n_rows)
{
    int e = blockIdx.x * 256 + threadIdx.x;
    if (e > nnz) return;
    int prev = (e == 0)   ? -1     : rows[e - 1];
    int cur  = (e == nnz) ? n_rows : rows[e];
    for (int r = prev + 1; r <= cur; ++r) rptr[r] = e;
}

// ---------------------------------------------------------------------------
// fp32 -> bf16 (RNE), vectorized. n4 = element_count / 4.
// ---------------------------------------------------------------------------
__global__ __launch_bounds__(256) void cvt_f32_bf16(
    const float* __restrict__ in, unsigned short* __restrict__ out, int n4)
{
    int i = blockIdx.x * 256 + threadIdx.x;
    if (i >= n4) return;
    float4 v = ((const float4*)in)[i];
    ushort4 o;
    o.x = f2b(v.x); o.y = f2b(v.y); o.z = f2b(v.z); o.w = f2b(v.w);
    ((ushort4*)out)[i] = o;
}

// ---------------------------------------------------------------------------
// Build Bt[4][256][512] bf16: Bt[l*2+e][n][k] = (k<256 ? Wside : Wdot)[l][k%256][n]
// ---------------------------------------------------------------------------
__global__ __launch_bounds__(256) void build_bt(
    const float* __restrict__ Ws_u, const float* __restrict__ Wd_u,
    const float* __restrict__ Ws_i, const float* __restrict__ Wd_i,
    unsigned short* __restrict__ Bt)
{
    int idx = blockIdx.x * 256 + threadIdx.x;    // 4*256*512 total
    int k   = idx & 511;
    int n   = (idx >> 9) & 255;
    int buf = idx >> 17;                          // l*2 + e
    int l = buf >> 1, e = buf & 1;
    const float* Wside = e ? Ws_i : Ws_u;
    const float* Wdot  = e ? Wd_i : Wd_u;
    float v = (k < 256) ? Wside[((size_t)l * 256 + k)       * 256 + n]
                        : Wdot [((size_t)l * 256 + (k-256)) * 256 + n];
    Bt[idx] = f2b(v);
}

// ---------------------------------------------------------------------------
// Merged-entity dual SpMM.
//   grid = (NTOT/4, 2); one wave per output row r in [0, NTOT).
//   y=0 -> LI into A cols [0,256) ; y=1 -> L * ebs[r] into cols [256,512)
// cols/vals prefetched 64-wide once per row (kills in-loop dependent uniform
// loads); gathers are 16B/lane with lane-halves covering TWO nnz per wave-load
// (half the VMEM instructions, 2x gather ILP); halves combined by shfl_xor.
// ---------------------------------------------------------------------------
__global__ __launch_bounds__(256) void spmm_dual_v2(
    const int* __restrict__ rpA_u, const int* __restrict__ cA_u, const float* __restrict__ vA_u,
    const int* __restrict__ rpB_u, const int* __restrict__ cB_u, const float* __restrict__ vB_u,
    const int* __restrict__ rpA_i, const int* __restrict__ cA_i, const float* __restrict__ vA_i,
    const int* __restrict__ rpB_i, const int* __restrict__ cB_i, const float* __restrict__ vB_i,
    const unsigned short* __restrict__ src,   // [NTOT,256] bf16
    unsigned short* __restrict__ out)         // [NTOT,512] bf16
{
    const int wave = threadIdx.x >> 6;
    const int lane = threadIdx.x & 63;
    const int r    = blockIdx.x * 4 + wave;
    if (r >= NTOT) return;
    const int  isB = blockIdx.y;
    const bool isI = (r >= NUQ);
    const int  row = isI ? (r - NUQ) : r;

    const int* rptr; const int* cols; const float* vals;
    if (isB) { rptr = isI ? rpB_i : rpB_u; cols = isI ? cB_i : cB_u; vals = isI ? vB_i : vB_u; }
    else     { rptr = isI ? rpA_i : rpA_u; cols = isI ? cA_i : cA_u; vals = isI ? vA_i : vA_u; }

    const int start = rptr[row];
    const int end   = rptr[row + 1];

    const int half = lane >> 5;    // which nnz of the current pair
    const int li   = lane & 31;    // dims [li*8, li*8+8)

    float acc[8] = {0.f, 0.f, 0.f, 0.f, 0.f, 0.f, 0.f, 0.f};

    for (int base = start; base < end; base += 64) {
        int cnt = end - base; if (cnt > 64) cnt = 64;
        int myc = 0; float myv = 0.f;
        if (lane < cnt) { myc = cols[base + lane]; myv = vals[base + lane]; }
        #pragma unroll 2
        for (int e = 0; e < cnt; e += 2) {
            const int idx = e + half;          // <= 63 always (e even, cnt<=64)
            const int   c = __shfl(myc, idx, 64);   // 0 / 0.f past cnt -> no-op
            const float v = __shfl(myv, idx, 64);
            const ushort8 s = *(const ushort8*)(src + (size_t)c * DQ + li * 8);
            #pragma unroll
            for (int j = 0; j < 8; ++j) acc[j] = fmaf(v, b2f(s[j]), acc[j]);
        }
    }

    #pragma unroll
    for (int j = 0; j < 8; ++j) acc[j] += __shfl_xor(acc[j], 32, 64);

    if (half == 0) {
        if (isB) {  // multiply by ebs[r] slice: merged layout makes mul == src row r
            const ushort8 m = *(const ushort8*)(src + (size_t)r * DQ + li * 8);
            #pragma unroll
            for (int j = 0; j < 8; ++j) acc[j] *= b2f(m[j]);
        }
        ushort8 o;
        #pragma unroll
        for (int j = 0; j < 8; ++j) o[j] = f2b(acc[j]);
        *(ushort8*)(out + (size_t)r * 512 + isB * 256 + li * 8) = o;
    }
}

// ---------------------------------------------------------------------------
// Merged-entity MFMA GEMM + leaky_relu, fused bf16 epilogue.
//   out[r,0:256] = leaky( A[r,0:512] @ Bt[ent]^T ),  ent = r >= 50000
//   64x256 tile (full N -> each A row read ONCE), BK=32, 4 waves (2x2 of
//   32x128), double-buffered LDS, 2-phase pipeline: stage k+1 before
//   computing k, ONE __syncthreads per k-step (its vmcnt+lgkm drain is the
//   pipeline fence).
//   LDS unit-t scheme (identical to verified 128x128 kernel): unit t (16B)
//   <-> m=((t>>6)<<4)|(t&15), kblk=(t>>4)&3, lds byte off = t*16.
//   global_load_lds LDS base is WAVE-UNIFORM (HW writes base + lane*16);
//   per-lane global addresses arranged so lane l's data is unit t=chunk*64+l.
// ---------------------------------------------------------------------------
__global__ __launch_bounds__(256) void gemm_mfma_leaky_v2(
    const unsigned short* __restrict__ A,     // [NTOT,512] bf16
    const unsigned short* __restrict__ Btl,   // layer base: 2 bufs of [256,512]
    float* __restrict__ out,                  // [NTOT,256] fp32 (layer base)
    unsigned short* __restrict__ ebs,         // [NTOT,256] bf16 next-layer input
    const int wb)                             // write bf16 copy?
{
    __shared__ unsigned short As[2][2048];    // 64 rows x 32 k  (2x 4 KB)
    __shared__ unsigned short Bs[2][8192];    // 256 n  x 32 k  (2x 16 KB)

    const int tid  = threadIdx.x;
    const int lane = tid & 63;
    const int w    = tid >> 6;
    const int ent  = (blockIdx.x >= GPE) ? 1 : 0;
    const int bx   = blockIdx.x - ent * GPE;
    const int row0 = ent * NUQ + bx * 64;
    const int Mend = ent * NUQ + NUQ;
    const unsigned short* Bt = Btl + (size_t)ent * 131072;

    // A staging: unit t = tid = w*64 + lane. Wave-uniform LDS base = w*512 shorts.
    const int mA  = ((tid >> 6) << 4) | (tid & 15);
    const int kbA = (tid >> 4) & 3;
    int grs = row0 + mA; if (grs >= Mend) grs = Mend - 1;   // clamp (safe garbage)
    const unsigned short* gA = A + (size_t)grs * 512 + kbA * 8;
    const int ldsA = w * 512;                                // shorts

    // B staging: chunk j covers units t = j*256 + tid; wave base = j*2048+w*512.
    const unsigned short* gB[4];
    #pragma unroll
    for (int j = 0; j < 4; ++j) {
        int t = j * 256 + tid;
        int n = ((t >> 6) << 4) | (t & 15);
        gB[j] = Bt + (size_t)n * 512 + ((t >> 4) & 3) * 8;
    }
    const int ldsB = w * 512;                                // + j*2048 shorts

    const int lr  = lane >> 4;      // 0..3 (kblk)
    const int lc  = lane & 15;
    const int gmb = (w & 1) * 2;    // A 16-row-group base
    const int gnb = (w >> 1) * 8;   // B 16-col-group base

    floatx4 acc[2][8] = {};

    // prologue: stage tile 0
    GLD_LDS16(gA, &As[0][ldsA]);
    #pragma unroll
    for (int j = 0; j < 4; ++j)
        GLD_LDS16(gB[j], &Bs[0][j * 2048 + ldsB]);
    __syncthreads();

    int cur = 0;
    for (int kt = 0; kt < 16; ++kt) {
        if (kt < 15) {  // issue next-tile staging BEFORE compute (overlaps)
            const int ko = (kt + 1) * 32;
            GLD_LDS16(gA + ko, &As[cur ^ 1][ldsA]);
            #pragma unroll
            for (int j = 0; j < 4; ++j)
                GLD_LDS16(gB[j] + ko, &Bs[cur ^ 1][j * 2048 + ldsB]);
        }

        bf16x8 af[2], bfr[8];
        #pragma unroll
        for (int tm = 0; tm < 2; ++tm)
            af[tm] = *(const bf16x8*)&As[cur][(gmb + tm) * 512 + lr * 128 + lc * 8];
        #pragma unroll
        for (int tn = 0; tn < 8; ++tn)
            bfr[tn] = *(const bf16x8*)&Bs[cur][(gnb + tn) * 512 + lr * 128 + lc * 8];

        #pragma unroll
        for (int tm = 0; tm < 2; ++tm)
            #pragma unroll
            for (int tn = 0; tn < 8; ++tn)
                acc[tm][tn] = __builtin_amdgcn_mfma_f32_16x16x32_bf16(
                    af[tm], bfr[tn], acc[tm][tn], 0, 0, 0);

        __syncthreads();   // drains vmcnt (next tile staged) + lgkm, barrier
        cur ^= 1;
    }

    // epilogue: C/D layout col=lane&15, row=(lane>>4)*4+r  [verified m89/m91]
    const int m_off = (w & 1) * 32;
    const int n_off = (w >> 1) * 128;
    #pragma unroll
    for (int tm = 0; tm < 2; ++tm) {
        #pragma unroll
        for (int rr = 0; rr < 4; ++rr) {
            const int gr = row0 + m_off + tm * 16 + lr * 4 + rr;
            if (gr >= Mend) continue;
            float*          orow = out + (size_t)gr * 256;
            unsigned short* brow = ebs + (size_t)gr * 256;
            #pragma unroll
            for (int tn = 0; tn < 8; ++tn) {
                const int gc = n_off + tn * 16 + lc;
                float v = acc[tm][tn][rr];
                v = v > 0.f ? v : LALPHA * v;
                orow[gc] = v;
                if (wb) brow[gc] = f2b(v);
            }
        }
    }
}

// ---------------------------------------------------------------------------
extern "C" void kernel_launch(void* const* d_in, const int* in_sizes, int n_in,
                              void* d_out, int out_size, void* d_ws, size_t ws_size,
                              hipStream_t stream) {
    const float* ebs0      = (const float*)d_in[0];
    const float* W_side_u  = (const float*)d_in[1];
    const float* W_dot_u   = (const float*)d_in[2];
    const float* W_side_i  = (const float*)d_in[3];
    const float* W_dot_i   = (const float*)d_in[4];
    const float* LI_vals_u = (const float*)d_in[5];
    const int*   LI_rows_u = (const int*)  d_in[6];
    const int*   LI_cols_u = (const int*)  d_in[7];
    const float* L_vals_u  = (const float*)d_in[8];
    const int*   L_rows_u  = (const int*)  d_in[9];
    const int*   L_cols_u  = (const int*)  d_in[10];
    const float* LI_vals_i = (const float*)d_in[11];
    const int*   LI_rows_i = (const int*)  d_in[12];
    const int*   LI_cols_i = (const int*)  d_in[13];
    const float* L_vals_i  = (const float*)d_in[14];
    const int*   L_rows_i  = (const int*)  d_in[15];
    const int*   L_cols_i  = (const int*)  d_in[16];

    float* out = (float*)d_out;

    // ws layout (bytes):
    //   [0, 102.4M)          Abuf    [100000,512] bf16
    //   [102.4M, 153.6M)     ebs_bf  [100000,256] bf16
    //   [153.6M, +1M)        Bt      [4][256][512] bf16
    //   [.., +0.8M)          rptr x4
    unsigned short* Abuf   = (unsigned short*)d_ws;
    unsigned short* ebs_bf = (unsigned short*)((char*)d_ws + 102400000);
    unsigned short* Bt     = (unsigned short*)((char*)d_ws + 153600000);
    int* rp_LI_u = (int*)((char*)d_ws + 154648576);
    int* rp_L_u  = rp_LI_u + 50001;
    int* rp_LI_i = rp_L_u  + 50001;
    int* rp_L_i  = rp_LI_i + 50001;

    const int nnz_LI_u = in_sizes[5];
    const int nnz_L_u  = in_sizes[8];
    const int nnz_LI_i = in_sizes[11];
    const int nnz_L_i  = in_sizes[14];

    dim3 b256(256);
    build_rowptr<<<dim3((nnz_LI_u + 256) / 256), b256, 0, stream>>>(LI_rows_u, nnz_LI_u, rp_LI_u, NUQ);
    build_rowptr<<<dim3((nnz_L_u  + 256) / 256), b256, 0, stream>>>(L_rows_u,  nnz_L_u,  rp_L_u,  NUQ);
    build_rowptr<<<dim3((nnz_LI_i + 256) / 256), b256, 0, stream>>>(LI_rows_i, nnz_LI_i, rp_LI_i, NIQ);
    build_rowptr<<<dim3((nnz_L_i  + 256) / 256), b256, 0, stream>>>(L_rows_i,  nnz_L_i,  rp_L_i,  NIQ);
    build_bt<<<dim3(2048), b256, 0, stream>>>(W_side_u, W_dot_u, W_side_i, W_dot_i, Bt);
    cvt_f32_bf16<<<dim3(25000), b256, 0, stream>>>(ebs0, ebs_bf, NTOT * DQ / 4);

    dim3 sgrid(NTOT / 4, 2);   // 25000 x 2, one wave per row
    dim3 ggrid(2 * GPE);       // 1564 blocks, entity by blockIdx

    for (int l = 0; l < 2; ++l) {
        float* outl = out + (size_t)l * NTOT * DQ;
        spmm_dual_v2<<<sgrid, b256, 0, stream>>>(
            rp_LI_u, LI_cols_u, LI_vals_u, rp_L_u, L_cols_u, L_vals_u,
            rp_LI_i, LI_cols_i, LI_vals_i, rp_L_i, L_cols_i, L_vals_i,
            ebs_bf, Abuf);
        gemm_mfma_leaky_v2<<<ggrid, b256, 0, stream>>>(
            Abuf, Bt + (size_t)l * 2 * 131072, outl, ebs_bf, (l == 0) ? 1 : 0);
    }
}

// Round 3
// 706.505 us; speedup vs baseline: 1.0888x; 1.0428x over previous
//
#include <hip/hip_runtime.h>

#define NUQ 50000
#define NIQ 50000
#define DQ 256
#define NTOT 100000
#define LALPHA 0.2f
#define GPE 782   // gemm blocks per entity = ceil(50000/64)

typedef __attribute__((ext_vector_type(8))) __bf16 bf16x8;
typedef __attribute__((ext_vector_type(4))) float floatx4;
typedef __attribute__((ext_vector_type(8))) unsigned short ushort8;

__device__ __forceinline__ float b2f(unsigned short u) {
    unsigned int x = ((unsigned int)u) << 16;
    return __builtin_bit_cast(float, x);
}
__device__ __forceinline__ unsigned short f2b(float f) {
    unsigned int u = __builtin_bit_cast(unsigned int, f);
    u = u + 0x7FFFu + ((u >> 16) & 1u);   // round-to-nearest-even
    return (unsigned short)(u >> 16);
}

#define GLD_LDS16(g, l)                                                        \
    __builtin_amdgcn_global_load_lds(                                          \
        (const __attribute__((address_space(1))) void*)(g),                    \
        (__attribute__((address_space(3))) void*)(l), 16, 0, 0)

// ---------------------------------------------------------------------------
// CSR row_ptr from sorted rows[].
// ---------------------------------------------------------------------------
__global__ __launch_bounds__(256) void build_rowptr(
    const int* __restrict__ rows, int nnz, int* __restrict__ rptr, int n_rows)
{
    int e = blockIdx.x * 256 + threadIdx.x;
    if (e > nnz) return;
    int prev = (e == 0)   ? -1     : rows[e - 1];
    int cur  = (e == nnz) ? n_rows : rows[e];
    for (int r = prev + 1; r <= cur; ++r) rptr[r] = e;
}

// ---------------------------------------------------------------------------
// fp32 -> bf16 (RNE), vectorized. n4 = element_count / 4.
// ---------------------------------------------------------------------------
__global__ __launch_bounds__(256) void cvt_f32_bf16(
    const float* __restrict__ in, unsigned short* __restrict__ out, int n4)
{
    int i = blockIdx.x * 256 + threadIdx.x;
    if (i >= n4) return;
    float4 v = ((const float4*)in)[i];
    ushort4 o;
    o.x = f2b(v.x); o.y = f2b(v.y); o.z = f2b(v.z); o.w = f2b(v.w);
    ((ushort4*)out)[i] = o;
}

// ---------------------------------------------------------------------------
// Build Bt[4][256][512] bf16: Bt[l*2+e][n][k] = (k<256 ? Wside : Wdot)[l][k%256][n]
// ---------------------------------------------------------------------------
__global__ __launch_bounds__(256) void build_bt(
    const float* __restrict__ Ws_u, const float* __restrict__ Wd_u,
    const float* __restrict__ Ws_i, const float* __restrict__ Wd_i,
    unsigned short* __restrict__ Bt)
{
    int idx = blockIdx.x * 256 + threadIdx.x;    // 4*256*512 total
    int k   = idx & 511;
    int n   = (idx >> 9) & 255;
    int buf = idx >> 17;                          // l*2 + e
    int l = buf >> 1, e = buf & 1;
    const float* Wside = e ? Ws_i : Ws_u;
    const float* Wdot  = e ? Wd_i : Wd_u;
    float v = (k < 256) ? Wside[((size_t)l * 256 + k)       * 256 + n]
                        : Wdot [((size_t)l * 256 + (k-256)) * 256 + n];
    Bt[idx] = f2b(v);
}

// ---------------------------------------------------------------------------
// Fully merged SpMM: one wave per row r, handling BOTH LI (->cols [0,256))
// and L*ebs (->cols [256,512)). Both matrices' rptr/cols/vals loads issue
// concurrently and their gathers interleave (~8 in flight) -- doubles the
// per-wave MLP vs the v2 kernel and halves wave count. Epilogue: half-lanes
// 0 write the LI part, half-lanes 1 the mul'd L part -> one contiguous 1 KB
// row store per wave.
// ---------------------------------------------------------------------------
__global__ __launch_bounds__(256) void spmm_merged_v3(
    const int* __restrict__ rpA_u, const int* __restrict__ cA_u, const float* __restrict__ vA_u,
    const int* __restrict__ rpB_u, const int* __restrict__ cB_u, const float* __restrict__ vB_u,
    const int* __restrict__ rpA_i, const int* __restrict__ cA_i, const float* __restrict__ vA_i,
    const int* __restrict__ rpB_i, const int* __restrict__ cB_i, const float* __restrict__ vB_i,
    const unsigned short* __restrict__ src,   // [NTOT,256] bf16
    unsigned short* __restrict__ out)         // [NTOT,512] bf16
{
    const int wave = threadIdx.x >> 6;
    const int lane = threadIdx.x & 63;
    const int r    = __builtin_amdgcn_readfirstlane(blockIdx.x * 4 + wave);
    const bool isI = (r >= NUQ);
    const int  row = isI ? (r - NUQ) : r;

    const int*   rpA = isI ? rpA_i : rpA_u;
    const int*   cAp = isI ? cA_i  : cA_u;
    const float* vAp = isI ? vA_i  : vA_u;
    const int*   rpB = isI ? rpB_i : rpB_u;
    const int*   cBp = isI ? cB_i  : cB_u;
    const float* vBp = isI ? vB_i  : vB_u;

    const int sA = rpA[row], eA = rpA[row + 1];
    const int sB = rpB[row], eB = rpB[row + 1];

    const int half = lane >> 5;    // which nnz of the current pair
    const int li   = lane & 31;    // dims [li*8, li*8+8)

    float accA[8] = {0.f, 0.f, 0.f, 0.f, 0.f, 0.f, 0.f, 0.f};
    float accB[8] = {0.f, 0.f, 0.f, 0.f, 0.f, 0.f, 0.f, 0.f};

    int baseA = sA, baseB = sB;
    while (baseA < eA || baseB < eB) {
        int cntA = eA - baseA; cntA = cntA < 0 ? 0 : (cntA > 64 ? 64 : cntA);
        int cntB = eB - baseB; cntB = cntB < 0 ? 0 : (cntB > 64 ? 64 : cntB);
        int mycA = 0; float myvA = 0.f;
        if (lane < cntA) { mycA = cAp[baseA + lane]; myvA = vAp[baseA + lane]; }
        int mycB = 0; float myvB = 0.f;
        if (lane < cntB) { mycB = cBp[baseB + lane]; myvB = vBp[baseB + lane]; }
        const int mx = cntA > cntB ? cntA : cntB;
        #pragma unroll 2
        for (int e = 0; e < mx; e += 2) {
            if (e < cntA) {                       // wave-uniform branch
                const int   c = __shfl(mycA, e + half, 64);
                const float v = __shfl(myvA, e + half, 64);
                const ushort8 s = *(const ushort8*)(src + (size_t)c * DQ + li * 8);
                #pragma unroll
                for (int j = 0; j < 8; ++j) accA[j] = fmaf(v, b2f(s[j]), accA[j]);
            }
            if (e < cntB) {
                const int   c = __shfl(mycB, e + half, 64);
                const float v = __shfl(myvB, e + half, 64);
                const ushort8 s = *(const ushort8*)(src + (size_t)c * DQ + li * 8);
                #pragma unroll
                for (int j = 0; j < 8; ++j) accB[j] = fmaf(v, b2f(s[j]), accB[j]);
            }
        }
        baseA += 64; baseB += 64;
    }

    #pragma unroll
    for (int j = 0; j < 8; ++j) accA[j] += __shfl_xor(accA[j], 32, 64);
    #pragma unroll
    for (int j = 0; j < 8; ++j) accB[j] += __shfl_xor(accB[j], 32, 64);

    float vo[8];
    if (half == 0) {
        #pragma unroll
        for (int j = 0; j < 8; ++j) vo[j] = accA[j];
    } else {   // L part: multiply by ebs[r] slice (merged layout: src row r)
        const ushort8 m = *(const ushort8*)(src + (size_t)r * DQ + li * 8);
        #pragma unroll
        for (int j = 0; j < 8; ++j) vo[j] = accB[j] * b2f(m[j]);
    }
    ushort8 o;
    #pragma unroll
    for (int j = 0; j < 8; ++j) o[j] = f2b(vo[j]);
    *(ushort8*)(out + (size_t)r * 512 + half * 256 + li * 8) = o;
}

// ---------------------------------------------------------------------------
// Merged-entity MFMA GEMM + leaky_relu, fused bf16 epilogue.
//   out[r,0:256] = leaky( A[r,0:512] @ Bt[ent]^T ),  ent = r >= 50000
//   64x256 tile, BK=32, 4 waves (2x2 of 32x128), 16x16x32 MFMA.
//   Depth-2 prefetch with COUNTED vmcnt (T4): tiles kt and kt+1 always in
//   flight; per k-step: vmcnt(5) [my 5 loads of kt done] -> barrier [all
//   waves' kt done] -> ds_read frags -> lgkmcnt(0) -> barrier [buf reusable]
//   -> issue kt+2 into same buf -> setprio(1)+MFMA. vmcnt(0) only at kt=15.
//   LDS unit-t scheme identical to the harness-verified v2 kernel.
// ---------------------------------------------------------------------------
__global__ __launch_bounds__(256) void gemm_mfma_leaky_v3(
    const unsigned short* __restrict__ A,     // [NTOT,512] bf16
    const unsigned short* __restrict__ Btl,   // layer base: 2 bufs of [256,512]
    float* __restrict__ out,                  // [NTOT,256] fp32 (layer base)
    unsigned short* __restrict__ ebs,         // [NTOT,256] bf16 next-layer input
    const int wb)                             // write bf16 copy?
{
    __shared__ unsigned short As[2][2048];    // 64 rows x 32 k  (2x 4 KB)
    __shared__ unsigned short Bs[2][8192];    // 256 n  x 32 k  (2x 16 KB)

    const int tid  = threadIdx.x;
    const int lane = tid & 63;
    const int w    = tid >> 6;
    const int ent  = (blockIdx.x >= GPE) ? 1 : 0;
    const int bx   = blockIdx.x - ent * GPE;
    const int row0 = ent * NUQ + bx * 64;
    const int Mend = ent * NUQ + NUQ;
    const unsigned short* Bt = Btl + (size_t)ent * 131072;

    // A staging: unit t = tid = w*64 + lane. Wave-uniform LDS base = w*512 shorts.
    const int mA  = ((tid >> 6) << 4) | (tid & 15);
    const int kbA = (tid >> 4) & 3;
    int grs = row0 + mA; if (grs >= Mend) grs = Mend - 1;   // clamp (safe garbage)
    const unsigned short* gA = A + (size_t)grs * 512 + kbA * 8;
    const int ldsA = w * 512;                                // shorts

    // B staging: chunk j covers units t = j*256 + tid; wave base = j*2048+w*512.
    const unsigned short* gB[4];
    #pragma unroll
    for (int j = 0; j < 4; ++j) {
        int t = j * 256 + tid;
        int n = ((t >> 6) << 4) | (t & 15);
        gB[j] = Bt + (size_t)n * 512 + ((t >> 4) & 3) * 8;
    }
    const int ldsB = w * 512;                                // + j*2048 shorts

    const int lr  = lane >> 4;      // 0..3 (kblk)
    const int lc  = lane & 15;
    const int gmb = (w & 1) * 2;    // A 16-row-group base
    const int gnb = (w >> 1) * 8;   // B 16-col-group base

    floatx4 acc[2][8] = {};

    // prologue: stage tiles 0 and 1 (10 outstanding vmem ops)
    GLD_LDS16(gA, &As[0][ldsA]);
    #pragma unroll
    for (int j = 0; j < 4; ++j) GLD_LDS16(gB[j], &Bs[0][j * 2048 + ldsB]);
    GLD_LDS16(gA + 32, &As[1][ldsA]);
    #pragma unroll
    for (int j = 0; j < 4; ++j) GLD_LDS16(gB[j] + 32, &Bs[1][j * 2048 + ldsB]);

    for (int kt = 0; kt < 16; ++kt) {
        const int cur = kt & 1;
        if (kt < 15) asm volatile("s_waitcnt vmcnt(5)" ::: "memory");
        else         asm volatile("s_waitcnt vmcnt(0)" ::: "memory");
        __builtin_amdgcn_s_barrier();          // all waves' tile-kt staging done

        bf16x8 af[2], bfr[8];
        #pragma unroll
        for (int tm = 0; tm < 2; ++tm)
            af[tm] = *(const bf16x8*)&As[cur][(gmb + tm) * 512 + lr * 128 + lc * 8];
        #pragma unroll
        for (int tn = 0; tn < 8; ++tn)
            bfr[tn] = *(const bf16x8*)&Bs[cur][(gnb + tn) * 512 + lr * 128 + lc * 8];

        asm volatile("s_waitcnt lgkmcnt(0)" ::: "memory");
        __builtin_amdgcn_s_barrier();          // all waves done reading buf[cur]

        if (kt < 14) {                          // stage tile kt+2 into buf[cur]
            const int ko = (kt + 2) * 32;
            GLD_LDS16(gA + ko, &As[cur][ldsA]);
            #pragma unroll
            for (int j = 0; j < 4; ++j)
                GLD_LDS16(gB[j] + ko, &Bs[cur][j * 2048 + ldsB]);
        }

        __builtin_amdgcn_s_setprio(1);
        #pragma unroll
        for (int tm = 0; tm < 2; ++tm)
            #pragma unroll
            for (int tn = 0; tn < 8; ++tn)
                acc[tm][tn] = __builtin_amdgcn_mfma_f32_16x16x32_bf16(
                    af[tm], bfr[tn], acc[tm][tn], 0, 0, 0);
        __builtin_amdgcn_s_setprio(0);
    }

    // epilogue: C/D layout col=lane&15, row=(lane>>4)*4+r  [verified m89/m91]
    const int m_off = (w & 1) * 32;
    const int n_off = (w >> 1) * 128;
    #pragma unroll
    for (int tm = 0; tm < 2; ++tm) {
        #pragma unroll
        for (int rr = 0; rr < 4; ++rr) {
            const int gr = row0 + m_off + tm * 16 + lr * 4 + rr;
            if (gr >= Mend) continue;
            float*          orow = out + (size_t)gr * 256;
            unsigned short* brow = ebs + (size_t)gr * 256;
            #pragma unroll
            for (int tn = 0; tn < 8; ++tn) {
                const int gc = n_off + tn * 16 + lc;
                float v = acc[tm][tn][rr];
                v = v > 0.f ? v : LALPHA * v;
                orow[gc] = v;
                if (wb) brow[gc] = f2b(v);
            }
        }
    }
}

// ---------------------------------------------------------------------------
extern "C" void kernel_launch(void* const* d_in, const int* in_sizes, int n_in,
                              void* d_out, int out_size, void* d_ws, size_t ws_size,
                              hipStream_t stream) {
    const float* ebs0      = (const float*)d_in[0];
    const float* W_side_u  = (const float*)d_in[1];
    const float* W_dot_u   = (const float*)d_in[2];
    const float* W_side_i  = (const float*)d_in[3];
    const float* W_dot_i   = (const float*)d_in[4];
    const float* LI_vals_u = (const float*)d_in[5];
    const int*   LI_rows_u = (const int*)  d_in[6];
    const int*   LI_cols_u = (const int*)  d_in[7];
    const float* L_vals_u  = (const float*)d_in[8];
    const int*   L_rows_u  = (const int*)  d_in[9];
    const int*   L_cols_u  = (const int*)  d_in[10];
    const float* LI_vals_i = (const float*)d_in[11];
    const int*   LI_rows_i = (const int*)  d_in[12];
    const int*   LI_cols_i = (const int*)  d_in[13];
    const float* L_vals_i  = (const float*)d_in[14];
    const int*   L_rows_i  = (const int*)  d_in[15];
    const int*   L_cols_i  = (const int*)  d_in[16];

    float* out = (float*)d_out;

    // ws layout (bytes):
    //   [0, 102.4M)          Abuf    [100000,512] bf16
    //   [102.4M, 153.6M)     ebs_bf  [100000,256] bf16
    //   [153.6M, +1M)        Bt      [4][256][512] bf16
    //   [.., +0.8M)          rptr x4
    unsigned short* Abuf   = (unsigned short*)d_ws;
    unsigned short* ebs_bf = (unsigned short*)((char*)d_ws + 102400000);
    unsigned short* Bt     = (unsigned short*)((char*)d_ws + 153600000);
    int* rp_LI_u = (int*)((char*)d_ws + 154648576);
    int* rp_L_u  = rp_LI_u + 50001;
    int* rp_LI_i = rp_L_u  + 50001;
    int* rp_L_i  = rp_LI_i + 50001;

    const int nnz_LI_u = in_sizes[5];
    const int nnz_L_u  = in_sizes[8];
    const int nnz_LI_i = in_sizes[11];
    const int nnz_L_i  = in_sizes[14];

    dim3 b256(256);
    build_rowptr<<<dim3((nnz_LI_u + 256) / 256), b256, 0, stream>>>(LI_rows_u, nnz_LI_u, rp_LI_u, NUQ);
    build_rowptr<<<dim3((nnz_L_u  + 256) / 256), b256, 0, stream>>>(L_rows_u,  nnz_L_u,  rp_L_u,  NUQ);
    build_rowptr<<<dim3((nnz_LI_i + 256) / 256), b256, 0, stream>>>(LI_rows_i, nnz_LI_i, rp_LI_i, NIQ);
    build_rowptr<<<dim3((nnz_L_i  + 256) / 256), b256, 0, stream>>>(L_rows_i,  nnz_L_i,  rp_L_i,  NIQ);
    build_bt<<<dim3(2048), b256, 0, stream>>>(W_side_u, W_dot_u, W_side_i, W_dot_i, Bt);
    cvt_f32_bf16<<<dim3(25000), b256, 0, stream>>>(ebs0, ebs_bf, NTOT * DQ / 4);

    dim3 sgrid(NTOT / 4);      // 25000 blocks, one wave per row (both matrices)
    dim3 ggrid(2 * GPE);       // 1564 blocks, entity by blockIdx

    for (int l = 0; l < 2; ++l) {
        float* outl = out + (size_t)l * NTOT * DQ;
        spmm_merged_v3<<<sgrid, b256, 0, stream>>>(
            rp_LI_u, LI_cols_u, LI_vals_u, rp_L_u, L_cols_u, L_vals_u,
            rp_LI_i, LI_cols_i, LI_vals_i, rp_L_i, L_cols_i, L_vals_i,
            ebs_bf, Abuf);
        gemm_mfma_leaky_v3<<<ggrid, b256, 0, stream>>>(
            Abuf, Bt + (size_t)l * 2 * 131072, outl, ebs_bf, (l == 0) ? 1 : 0);
    }
}